// Round 6
// baseline (63.144 us; speedup 1.0000x reference)
//
#include <hip/hip_runtime.h>
#include <cstddef>

// Problem constants
#define NB 4
#define LQ 512
#define LK 512
#define QF 256
#define NH 128
#define VD 256

__device__ __forceinline__ float fexp2(float x) {
    float r; asm("v_exp_f32 %0, %1" : "=v"(r) : "v"(x)); return r;
}
__device__ __forceinline__ float frcp(float x) {
    float r; asm("v_rcp_f32 %0, %1" : "=v"(r) : "v"(x)); return r;
}
__device__ __forceinline__ void fma4(float4& acc, float s, const float4 v) {
    acc.x = __builtin_fmaf(s, v.x, acc.x);
    acc.y = __builtin_fmaf(s, v.y, acc.y);
    acc.z = __builtin_fmaf(s, v.z, acc.z);
    acc.w = __builtin_fmaf(s, v.w, acc.w);
}

constexpr float kLog2e    = 1.4426950408889634f;
constexpr float kPreScale = 2.0f * kLog2e;   // tanh(x) = 1 - 2/(1 + exp2(kPreScale*x))

// ---------------------------------------------------------------------------
// K0: transpose W_q, W_k into f4-major float4 tiles (unchanged from R5).
// ---------------------------------------------------------------------------
__global__ __launch_bounds__(256) void transw_kernel(
    const float* __restrict__ W_q, const float* __restrict__ W_k,
    float4* __restrict__ wt)
{
    const int bid = blockIdx.x;          // 16 = 2 mats * 8 f4-groups
    const int mat = bid & 1;
    const int f4b = (bid >> 1) * 8;
    const float4* W4 = (const float4*)(mat ? W_k : W_q);
    float4* o = wt + (size_t)mat * 64 * NH;

    const int t  = threadIdx.x;
    const int h  = t & 127;
    const int fo = t >> 7;
    #pragma unroll
    for (int it = 0; it < 4; ++it) {
        const int f4 = f4b + fo + 2 * it;
        o[f4 * NH + h] = W4[h * 64 + f4];
    }
}

// ---------------------------------------------------------------------------
// K1: projections + exponentials (unchanged from R5).
//   eq [row][h]  = exp2(kPreScale * (Q·Wq^T))   row-major [2048][128]
//   ekt[b][h][j] = exp2(kPreScale * (K·Wk^T))   transposed [4][128][512]
// ---------------------------------------------------------------------------
#define ETS 132

__global__ __launch_bounds__(256) void proj_kernel(
    const float* __restrict__ queries, const float* __restrict__ keys,
    const float4* __restrict__ wt,
    float* __restrict__ eq, float* __restrict__ ekt)
{
    const int bid   = blockIdx.x;        // 256 = 2 which * 128 row-tiles(16)
    const int which = bid & 1;
    const int rt    = bid >> 1;
    const int row0  = rt * 16;
    const float4* In4 = (const float4*)(which ? keys : queries);
    const float4* w4  = wt + (size_t)which * 64 * NH;

    __shared__ float4 rows[16][64];      // 16KB; later aliased as et[16][ETS]

    const int t    = threadIdx.x;
    const int lane = t & 63;
    const int wid  = t >> 6;

    {
        const int f4 = t & 63;
        const int r0 = t >> 6;
        #pragma unroll
        for (int k = 0; k < 4; ++k) {
            const int r = r0 + 4 * k;
            rows[r][f4] = In4[(size_t)(row0 + r) * 64 + f4];
        }
    }
    __syncthreads();

    const int rbase = wid * 4;
    float acc[4][2] = {};
    #pragma unroll 2
    for (int f4 = 0; f4 < 64; ++f4) {
        const float4 w0 = w4[f4 * NH + lane];
        const float4 w1 = w4[f4 * NH + lane + 64];
        #pragma unroll
        for (int r = 0; r < 4; ++r) {
            const float4 x = rows[rbase + r][f4];    // wave-uniform broadcast
            acc[r][0] += w0.x * x.x + w0.y * x.y + w0.z * x.z + w0.w * x.w;
            acc[r][1] += w1.x * x.x + w1.y * x.y + w1.z * x.z + w1.w * x.w;
        }
    }

    if (which == 0) {
        #pragma unroll
        for (int r = 0; r < 4; ++r) {
            const size_t o = (size_t)(row0 + rbase + r) * NH;
            eq[o + lane]      = fexp2(kPreScale * acc[r][0]);
            eq[o + lane + 64] = fexp2(kPreScale * acc[r][1]);
        }
    } else {
        __syncthreads();
        float* et = (float*)rows;        // [16][ETS]
        #pragma unroll
        for (int r = 0; r < 4; ++r) {
            et[(rbase + r) * ETS + lane]      = fexp2(kPreScale * acc[r][0]);
            et[(rbase + r) * ETS + lane + 64] = fexp2(kPreScale * acc[r][1]);
        }
        __syncthreads();
        const int rl = t & 15;
        const int h0 = t >> 4;
        const int b  = row0 >> 9;
        const int j0 = row0 & 511;
        #pragma unroll
        for (int pass = 0; pass < 8; ++pass) {
            const int hh = h0 + 16 * pass;
            ekt[((size_t)b * NH + hh) * LK + j0 + rl] = et[rl * ETS + hh];
        }
    }
}

// ---------------------------------------------------------------------------
// K2 (FUSED): scores + softmax-sum + attn write + PV + out, one kernel.
// Block = (b, 4-query tile); 1024 threads = 16 waves; grid 512 batch-
// interleaved (id&3 = b) so co-resident blocks mix batches (valid_len
// balance); 2 rounds of ~256 resident blocks give early-finish rebalancing.
//
// Phase S: wave (qi = w&3, g = w>>2) computes p = exp(s - M) for query qi,
//   chunks {g, g+4} (M = sum|W_v| >= max score, so no row-max pass; p<=1,
//   p>=e^-18: fp32-safe — validated R4/R5). p masked to 0 for j>=vl at the
//   source. p stays in REGISTERS (no global round-trip, R4/R5's 8 MB saved).
// Norm: shfl sum -> reds[16] -> rs; attn written to global (coalesced) and
//   to attn_t[j][4] in LDS (q-vectorized for PV).
// Phase PV: wave w owns j-strip [32w, 32w+32): per j, 1 uniform b128 read
//   gives all 4 q-weights, 1 coalesced 1KB values load, 16 fma. Two-round
//   pacc reduce (waves 0-7 write, 8-15 add), final 8-way sum -> out.
// LDS ~43 KB.
// ---------------------------------------------------------------------------
__global__ __launch_bounds__(1024) void fused_kernel(
    const float* __restrict__ eq, const float* __restrict__ ekt,
    const float* __restrict__ values, const int* __restrict__ valid_lens,
    const float* __restrict__ W_v,
    float* __restrict__ out, float* __restrict__ attn_out)
{
    const int id = blockIdx.x;           // 512 = 128 qt * 4 b (b fastest)
    const int b  = id & 3;
    const int i0 = (id >> 2) * 4;
    const int vl = valid_lens[b];

    __shared__ float  eq_lds[4][NH];
    __shared__ float  wv[NH];
    __shared__ float  attn_t[LK][4];     // [j][q], rows 16B-aligned
    __shared__ float4 pacc[8][4][VD / 4];
    __shared__ float  reds[16];

    const int t    = threadIdx.x;
    const int wid  = t >> 6;
    const int lane = t & 63;
    const int qi   = wid & 3;
    const int g    = wid >> 2;

    if (t < 4 * NH) ((float*)eq_lds)[t] = eq[(size_t)(b * LQ + i0) * NH + t];
    if (t < NH)     wv[t] = W_v[t];
    __syncthreads();

    const float4* q4  = (const float4*)eq_lds[qi];
    const float4* wv4 = (const float4*)wv;

    float sumA = 0.f, sumW = 0.f;
    #pragma unroll 8
    for (int h4 = 0; h4 < NH / 4; ++h4) {
        const float4 w = wv4[h4];
        sumW += (w.x + w.y) + (w.z + w.w);
        sumA += (fabsf(w.x) + fabsf(w.y)) + (fabsf(w.z) + fabsf(w.w));
    }

    // ---- Phase S: p for chunks {g, g+4} of query qi ----
    float p[2];
    float sum = 0.f;
    #pragma unroll
    for (int u = 0; u < 2; ++u) {
        const int jj = g + 4 * u;
        const int j  = jj * 64 + lane;
        float pv = 0.f;
        if (jj * 64 < vl) {              // wave-uniform
            const float* pk = ekt + (size_t)b * NH * LK + j;
            float a0 = 0.f, a1 = 0.f, a2 = 0.f, a3 = 0.f;
            #pragma unroll 4
            for (int h4 = 0; h4 < NH / 4; ++h4) {
                const float e0 = pk[(size_t)(4 * h4 + 0) * LK];   // coalesced 256B
                const float e1 = pk[(size_t)(4 * h4 + 1) * LK];
                const float e2 = pk[(size_t)(4 * h4 + 2) * LK];
                const float e3 = pk[(size_t)(4 * h4 + 3) * LK];
                const float4 w = wv4[h4];
                const float4 q = q4[h4];
                a0 = __builtin_fmaf(w.x, frcp(__builtin_fmaf(q.x, e0, 1.f)), a0);
                a1 = __builtin_fmaf(w.y, frcp(__builtin_fmaf(q.y, e1, 1.f)), a1);
                a2 = __builtin_fmaf(w.z, frcp(__builtin_fmaf(q.z, e2, 1.f)), a2);
                a3 = __builtin_fmaf(w.w, frcp(__builtin_fmaf(q.w, e3, 1.f)), a3);
            }
            const float s = __builtin_fmaf(-2.f, (a0 + a1) + (a2 + a3), sumW);
            pv = fexp2((s - sumA) * kLog2e);
            if (j >= vl) pv = 0.f;       // mask tail of boundary chunk
        }
        p[u] = pv;
        sum += pv;
    }

    // ---- normalize: per-query sum across 4 g-waves ----
    #pragma unroll
    for (int off = 1; off < 64; off <<= 1)
        sum += __shfl_xor(sum, off, 64);
    if (lane == 0) reds[wid] = sum;
    __syncthreads();
    const float rs = frcp((reds[qi] + reds[qi + 4]) + (reds[qi + 8] + reds[qi + 12]));

    float* arow = attn_out + (size_t)(b * LQ + i0 + qi) * LK;
    #pragma unroll
    for (int u = 0; u < 2; ++u) {
        const int j = (g + 4 * u) * 64 + lane;
        const float a = p[u] * rs;
        arow[j]       = a;               // coalesced; zeros beyond vl
        attn_t[j][qi] = a;
    }
    __syncthreads();

    // ---- Phase PV ----
    const int j0 = wid * 32;
    const int j1 = min(j0 + 32, vl);     // attn_t exactly 0 in [vl, LK)
    float4 acc4[4];
    #pragma unroll
    for (int q = 0; q < 4; ++q) acc4[q] = float4{0.f, 0.f, 0.f, 0.f};

    const float4* v4 = (const float4*)(values + (size_t)b * LK * VD);
    for (int j = j0; j < j1; ++j) {
        const float4 a  = *(const float4*)&attn_t[j][0];   // all 4 q (uniform)
        const float4 vv = v4[(size_t)j * 64 + lane];       // coalesced 1KB
        fma4(acc4[0], a.x, vv);
        fma4(acc4[1], a.y, vv);
        fma4(acc4[2], a.z, vv);
        fma4(acc4[3], a.w, vv);
    }

    if (wid < 8) {
        #pragma unroll
        for (int q = 0; q < 4; ++q) pacc[wid][q][lane] = acc4[q];
    }
    __syncthreads();
    if (wid >= 8) {
        #pragma unroll
        for (int q = 0; q < 4; ++q) {
            const float4 pv = pacc[wid - 8][q][lane];
            pacc[wid - 8][q][lane] =
                float4{pv.x + acc4[q].x, pv.y + acc4[q].y,
                       pv.z + acc4[q].z, pv.w + acc4[q].w};
        }
    }
    __syncthreads();

    {   // final reduce: thread -> (q = t>>8, c = t&255)
        const int q = t >> 8;
        const int c = t & 255;
        float s = 0.f;
        #pragma unroll
        for (int k = 0; k < 8; ++k)
            s += ((const float*)&pacc[k][q][0])[c];
        out[(size_t)(b * LQ + i0 + q) * VD + c] = s;
    }
}

// ---------------------------------------------------------------------------
extern "C" void kernel_launch(void* const* d_in, const int* in_sizes, int n_in,
                              void* d_out, int out_size, void* d_ws, size_t ws_size,
                              hipStream_t stream)
{
    const float* queries    = (const float*)d_in[0];
    const float* keys       = (const float*)d_in[1];
    const float* values     = (const float*)d_in[2];
    const int*   valid_lens = (const int*)  d_in[3];
    const float* W_q        = (const float*)d_in[4];
    const float* W_k        = (const float*)d_in[5];
    const float* W_v        = (const float*)d_in[6];

    float* out      = (float*)d_out;                       // [NB, LQ, VD]
    float* attn_out = out + (size_t)NB * LQ * VD;          // [NB, LQ, LK]

    float*  eq  = (float*)d_ws;                            // [2048][128]  1MB
    float*  ekt = eq + (size_t)NB * LQ * NH;               // [4][128][512] 1MB
    float4* wt  = (float4*)(ekt + (size_t)NB * NH * LK);   // [2][64][128] 256KB

    transw_kernel<<<16,  256,  0, stream>>>(W_q, W_k, wt);
    proj_kernel  <<<256, 256,  0, stream>>>(queries, keys, wt, eq, ekt);
    fused_kernel <<<512, 1024, 0, stream>>>(eq, ekt, values, valid_lens, W_v,
                                            out, attn_out);
}

// Round 7
// 60.752 us; speedup vs baseline: 1.0394x; 1.0394x over previous
//
#include <hip/hip_runtime.h>
#include <cstddef>

// Problem constants
#define NB 4
#define LQ 512
#define LK 512
#define QF 256
#define NH 128
#define VD 256

__device__ __forceinline__ float fexp2(float x) {
    float r; asm("v_exp_f32 %0, %1" : "=v"(r) : "v"(x)); return r;
}
__device__ __forceinline__ float frcp(float x) {
    float r; asm("v_rcp_f32 %0, %1" : "=v"(r) : "v"(x)); return r;
}
__device__ __forceinline__ void fma4(float4& acc, float s, const float4 v) {
    acc.x = __builtin_fmaf(s, v.x, acc.x);
    acc.y = __builtin_fmaf(s, v.y, acc.y);
    acc.z = __builtin_fmaf(s, v.z, acc.z);
    acc.w = __builtin_fmaf(s, v.w, acc.w);
}

constexpr float kLog2e    = 1.4426950408889634f;
constexpr float kPreScale = 2.0f * kLog2e;   // tanh(x) = 1 - 2/(1 + exp2(kPreScale*x))

// ---------------------------------------------------------------------------
// K0: transpose W_q, W_k into f4-major float4 tiles (unchanged).
//   wt[mat][f4][h] = float4{ W[h][4*f4 .. 4*f4+3] }
// ---------------------------------------------------------------------------
__global__ __launch_bounds__(256) void transw_kernel(
    const float* __restrict__ W_q, const float* __restrict__ W_k,
    float4* __restrict__ wt)
{
    const int bid = blockIdx.x;          // 16 = 2 mats * 8 f4-groups
    const int mat = bid & 1;
    const int f4b = (bid >> 1) * 8;
    const float4* W4 = (const float4*)(mat ? W_k : W_q);
    float4* o = wt + (size_t)mat * 64 * NH;

    const int t  = threadIdx.x;
    const int h  = t & 127;
    const int fo = t >> 7;
    #pragma unroll
    for (int it = 0; it < 4; ++it) {
        const int f4 = f4b + fo + 2 * it;
        o[f4 * NH + h] = W4[h * 64 + f4];
    }
}

// ---------------------------------------------------------------------------
// K1: projections + exponentials.  8-row tiles -> 512 blocks = 2048 waves
// (R6's 1024 waves = 1/SIMD was latency-naked).  Outputs:
//   eq  [row][h]              = exp2(ps * Q.Wq^T)       [2048][128]
//   ekt4[b][h4][j][c]  (f32)  = exp2(ps * K.Wk^T), h=4*h4+c  -> score reads
//                               one float4 = 4 h-values per (j, h4)
// Direct scattered stores for ekt4 (16B per 4-lane group; ~1MB total, cheap)
// replace R5/R6's LDS-alias transpose.
// ---------------------------------------------------------------------------
__global__ __launch_bounds__(256) void proj_kernel(
    const float* __restrict__ queries, const float* __restrict__ keys,
    const float4* __restrict__ wt,
    float* __restrict__ eq, float* __restrict__ ekt4f)
{
    const int bid   = blockIdx.x;        // 512 = 2 which * 256 row-tiles(8)
    const int which = bid & 1;
    const int rt    = bid >> 1;
    const int row0  = rt * 8;
    const float4* In4 = (const float4*)(which ? keys : queries);
    const float4* w4  = wt + (size_t)which * 64 * NH;

    __shared__ float4 rows[8][64];       // 8KB

    const int t    = threadIdx.x;
    const int lane = t & 63;
    const int wid  = t >> 6;

    {   // stage 8 rows, coalesced
        const int f4 = t & 63;
        const int r  = t >> 6;
        rows[r][f4]     = In4[(size_t)(row0 + r) * 64 + f4];
        rows[r + 4][f4] = In4[(size_t)(row0 + r + 4) * 64 + f4];
    }
    __syncthreads();

    const int r0 = wid * 2;              // wave's 2 rows
    float acc[2][2] = {};
    #pragma unroll 4
    for (int f4 = 0; f4 < 64; ++f4) {
        const float4 w0 = w4[f4 * NH + lane];        // coalesced 1KB
        const float4 w1 = w4[f4 * NH + lane + 64];
        #pragma unroll
        for (int r = 0; r < 2; ++r) {
            const float4 x = rows[r0 + r][f4];       // wave-uniform broadcast
            acc[r][0] += w0.x * x.x + w0.y * x.y + w0.z * x.z + w0.w * x.w;
            acc[r][1] += w1.x * x.x + w1.y * x.y + w1.z * x.z + w1.w * x.w;
        }
    }

    if (which == 0) {
        #pragma unroll
        for (int r = 0; r < 2; ++r) {
            const size_t o = (size_t)(row0 + r0 + r) * NH;
            eq[o + lane]      = fexp2(kPreScale * acc[r][0]);
            eq[o + lane + 64] = fexp2(kPreScale * acc[r][1]);
        }
    } else {
        const int b  = row0 >> 9;
        const int j0 = (row0 & 511) + r0;
        #pragma unroll
        for (int r = 0; r < 2; ++r) {
            #pragma unroll
            for (int s = 0; s < 2; ++s) {
                const int h = lane + 64 * s;
                // float4-interleaved: [b][h>>2][j][h&3]
                ekt4f[(((size_t)b * 32 + (h >> 2)) * LK + j0 + r) * 4 + (h & 3)]
                    = fexp2(kPreScale * acc[r][s]);
            }
        }
    }
}

// ---------------------------------------------------------------------------
// K2: scores -> unnormalized numerators p = exp(s - M), M = sum|W_v|.
// Block = (b, 8-query tile, 64-key chunk); wave owns 2 queries sharing each
// Ek load; early exit for inactive chunks.  KEY CHANGE vs R6: Ek loads are
// float4 (4 h-values, 16B/lane, 1KB/wave) -> 32 VMEM instr per j instead of
// 128 scalar loads; 4x deeper load pipelining at same VGPR (R6 was latency-
// starved at VALUBusy 31%).
// ---------------------------------------------------------------------------
__global__ __launch_bounds__(256, 8) void score_kernel(
    const float* __restrict__ eq, const float* __restrict__ ekt4f,
    const int* __restrict__ valid_lens, const float* __restrict__ W_v,
    float* __restrict__ pout)
{
    const int id = blockIdx.x;           // 2048; b fastest for CU mixing
    const int b  = id & 3;
    const int jc = (id >> 2) & 7;
    const int it = id >> 5;              // 0..63
    const int vl = valid_lens[b];
    if (jc * 64 >= vl) return;           // uniform early exit

    __shared__ float q_lds[8][NH];
    __shared__ float wv[NH];

    const int t  = threadIdx.x;
    const int i0 = it * 8;
    #pragma unroll
    for (int r = 0; r < 4; ++r)
        ((float*)q_lds)[t + 256 * r] = eq[(size_t)(b * LQ + i0) * NH + t + 256 * r];
    if (t < NH) wv[t] = W_v[t];
    __syncthreads();

    const int wid  = t >> 6;
    const int lane = t & 63;
    const float4* qa4 = (const float4*)q_lds[2 * wid];
    const float4* qb4 = (const float4*)q_lds[2 * wid + 1];
    const float4* wv4 = (const float4*)wv;

    float sumW = 0.f, sumA = 0.f;
    #pragma unroll 8
    for (int h4 = 0; h4 < NH / 4; ++h4) {
        const float4 w = wv4[h4];
        sumW += (w.x + w.y) + (w.z + w.w);
        sumA += (fabsf(w.x) + fabsf(w.y)) + (fabsf(w.z) + fabsf(w.w));
    }

    const int j = jc * 64 + lane;
    const float4* pk4 = (const float4*)ekt4f + (size_t)b * 32 * LK + j;
    float aA0 = 0.f, aA1 = 0.f, aA2 = 0.f, aA3 = 0.f;
    float aB0 = 0.f, aB1 = 0.f, aB2 = 0.f, aB3 = 0.f;
    #pragma unroll 8
    for (int h4 = 0; h4 < NH / 4; ++h4) {
        const float4 e  = pk4[(size_t)h4 * LK];      // 16B/lane, 1KB/wave
        const float4 w  = wv4[h4];
        const float4 qa = qa4[h4];
        const float4 qb = qb4[h4];
        aA0 = __builtin_fmaf(w.x, frcp(__builtin_fmaf(qa.x, e.x, 1.f)), aA0);
        aA1 = __builtin_fmaf(w.y, frcp(__builtin_fmaf(qa.y, e.y, 1.f)), aA1);
        aA2 = __builtin_fmaf(w.z, frcp(__builtin_fmaf(qa.z, e.z, 1.f)), aA2);
        aA3 = __builtin_fmaf(w.w, frcp(__builtin_fmaf(qa.w, e.w, 1.f)), aA3);
        aB0 = __builtin_fmaf(w.x, frcp(__builtin_fmaf(qb.x, e.x, 1.f)), aB0);
        aB1 = __builtin_fmaf(w.y, frcp(__builtin_fmaf(qb.y, e.y, 1.f)), aB1);
        aB2 = __builtin_fmaf(w.z, frcp(__builtin_fmaf(qb.z, e.z, 1.f)), aB2);
        aB3 = __builtin_fmaf(w.w, frcp(__builtin_fmaf(qb.w, e.w, 1.f)), aB3);
    }
    const float sA = __builtin_fmaf(-2.f, (aA0 + aA1) + (aA2 + aA3), sumW);
    const float sB = __builtin_fmaf(-2.f, (aB0 + aB1) + (aB2 + aB3), sumW);
    const float pA = fexp2((sA - sumA) * kLog2e);
    const float pB = fexp2((sB - sumA) * kLog2e);

    const int ra = i0 + 2 * wid;
    pout[((size_t)b * LQ + ra)     * LK + j] = pA;
    pout[((size_t)b * LQ + ra + 1) * LK + j] = pB;
}

// ---------------------------------------------------------------------------
// K3: normalize + attn write + PV.  512 blocks (b, 4 queries) x 512 threads
// (8 waves), ~25KB LDS -> 4 blocks/CU by wave cap.  Phase A: wave (qi=w&3,
// g=w>>2) sums chunks {g,g+2,g+4,g+6}.  PV: wave w takes j = w, w+8, w+16...
// (stride-8 interleave -> balanced for any vl).
// ---------------------------------------------------------------------------
__global__ __launch_bounds__(512) void normpv_kernel(
    const float* __restrict__ values, const int* __restrict__ valid_lens,
    float* __restrict__ out, float* __restrict__ attn_out /* = p in */)
{
    const int id = blockIdx.x;           // 512; b fastest
    const int b  = id & 3;
    const int i0 = (id >> 2) * 4;
    const int vl = valid_lens[b];

    __shared__ float  attn_t[LK][4];     // [j][q] 8KB, rows 16B-aligned
    __shared__ float4 pacc[4][4][VD / 4];// 16KB
    __shared__ float  reds[8];

    const int t    = threadIdx.x;
    const int wid  = t >> 6;
    const int lane = t & 63;
    const int qi   = wid & 3;
    const int g    = wid >> 2;

    // ---- Phase A: per-query sum + normalize + attn writes ----
    float* arow = attn_out + (size_t)(b * LQ + i0 + qi) * LK;
    float p[4];
    float sum = 0.f;
    #pragma unroll
    for (int u = 0; u < 4; ++u) {
        const int jj = g + 2 * u;
        const int j  = jj * 64 + lane;
        float e = 0.f;
        if (jj * 64 < vl) {              // wave-uniform
            e = arow[j];
            if (j >= vl) e = 0.f;        // mask tail of boundary chunk
        }
        p[u] = e;
        sum += e;
    }
    #pragma unroll
    for (int off = 1; off < 64; off <<= 1)
        sum += __shfl_xor(sum, off, 64);
    if (lane == 0) reds[wid] = sum;
    __syncthreads();
    const float rs = frcp(reds[qi] + reds[qi + 4]);

    #pragma unroll
    for (int u = 0; u < 4; ++u) {
        const int j = (g + 2 * u) * 64 + lane;
        const float a = p[u] * rs;
        arow[j]       = a;               // coalesced; zeros beyond vl
        attn_t[j][qi] = a;
    }
    __syncthreads();

    // ---- Phase PV: stride-8 j-interleave across 8 waves ----
    float4 acc4[4];
    #pragma unroll
    for (int q = 0; q < 4; ++q) acc4[q] = float4{0.f, 0.f, 0.f, 0.f};

    const float4* v4 = (const float4*)(values + (size_t)b * LK * VD);
    for (int j = wid; j < vl; j += 8) {
        const float4 a  = *(const float4*)&attn_t[j][0];   // all 4 q (uniform)
        const float4 vv = v4[(size_t)j * 64 + lane];       // coalesced 1KB
        fma4(acc4[0], a.x, vv);
        fma4(acc4[1], a.y, vv);
        fma4(acc4[2], a.z, vv);
        fma4(acc4[3], a.w, vv);
    }

    if (wid < 4) {
        #pragma unroll
        for (int q = 0; q < 4; ++q) pacc[wid][q][lane] = acc4[q];
    }
    __syncthreads();
    if (wid >= 4) {
        #pragma unroll
        for (int q = 0; q < 4; ++q) {
            const float4 pv = pacc[wid - 4][q][lane];
            pacc[wid - 4][q][lane] =
                float4{pv.x + acc4[q].x, pv.y + acc4[q].y,
                       pv.z + acc4[q].z, pv.w + acc4[q].w};
        }
    }
    __syncthreads();

    {   // final reduce: thread -> (q = t>>7, cols c and c+128)
        const int q = t >> 7;
        const int c = t & 127;
        float s0 = 0.f, s1 = 0.f;
        #pragma unroll
        for (int k = 0; k < 4; ++k) {
            const float* pf = (const float*)&pacc[k][q][0];
            s0 += pf[c];
            s1 += pf[c + 128];
        }
        float* orow = out + (size_t)(b * LQ + i0 + q) * VD;
        orow[c]       = s0;
        orow[c + 128] = s1;
    }
}

// ---------------------------------------------------------------------------
extern "C" void kernel_launch(void* const* d_in, const int* in_sizes, int n_in,
                              void* d_out, int out_size, void* d_ws, size_t ws_size,
                              hipStream_t stream)
{
    const float* queries    = (const float*)d_in[0];
    const float* keys       = (const float*)d_in[1];
    const float* values     = (const float*)d_in[2];
    const int*   valid_lens = (const int*)  d_in[3];
    const float* W_q        = (const float*)d_in[4];
    const float* W_k        = (const float*)d_in[5];
    const float* W_v        = (const float*)d_in[6];

    float* out      = (float*)d_out;                       // [NB, LQ, VD]
    float* attn_out = out + (size_t)NB * LQ * VD;          // [NB, LQ, LK]

    float*  eq    = (float*)d_ws;                          // [2048][128]  1MB
    float*  ekt4f = eq + (size_t)NB * LQ * NH;             // [4][32][512][4] 1MB
    float4* wt    = (float4*)(ekt4f + (size_t)NB * NH * LK); // [2][64][128] 256KB

    transw_kernel<<<16,   256, 0, stream>>>(W_q, W_k, wt);
    proj_kernel  <<<512,  256, 0, stream>>>(queries, keys, wt, eq, ekt4f);
    score_kernel <<<2048, 256, 0, stream>>>(eq, ekt4f, valid_lens, W_v, attn_out);
    normpv_kernel<<<512,  512, 0, stream>>>(values, valid_lens, out, attn_out);
}

// Round 8
// 47.835 us; speedup vs baseline: 1.3200x; 1.2700x over previous
//
#include <hip/hip_runtime.h>
#include <cstddef>

// Problem constants
#define NB 4
#define LQ 512
#define LK 512
#define QF 256
#define NH 128
#define VD 256

__device__ __forceinline__ float fexp2(float x) {
    float r; asm("v_exp_f32 %0, %1" : "=v"(r) : "v"(x)); return r;
}
__device__ __forceinline__ float frcp(float x) {
    float r; asm("v_rcp_f32 %0, %1" : "=v"(r) : "v"(x)); return r;
}
__device__ __forceinline__ void fma4(float4& acc, float s, const float4 v) {
    acc.x = __builtin_fmaf(s, v.x, acc.x);
    acc.y = __builtin_fmaf(s, v.y, acc.y);
    acc.z = __builtin_fmaf(s, v.z, acc.z);
    acc.w = __builtin_fmaf(s, v.w, acc.w);
}

constexpr float kLog2e    = 1.4426950408889634f;
constexpr float kPreScale = 2.0f * kLog2e;   // tanh(x) = 1 - 2/(1 + exp2(kPreScale*x))

// ---------------------------------------------------------------------------
// K0: transpose W_q, W_k into f4-major float4 tiles (FROZEN from R7).
// ---------------------------------------------------------------------------
__global__ __launch_bounds__(256) void transw_kernel(
    const float* __restrict__ W_q, const float* __restrict__ W_k,
    float4* __restrict__ wt)
{
    const int bid = blockIdx.x;          // 16 = 2 mats * 8 f4-groups
    const int mat = bid & 1;
    const int f4b = (bid >> 1) * 8;
    const float4* W4 = (const float4*)(mat ? W_k : W_q);
    float4* o = wt + (size_t)mat * 64 * NH;

    const int t  = threadIdx.x;
    const int h  = t & 127;
    const int fo = t >> 7;
    #pragma unroll
    for (int it = 0; it < 4; ++it) {
        const int f4 = f4b + fo + 2 * it;
        o[f4 * NH + h] = W4[h * 64 + f4];
    }
}

// ---------------------------------------------------------------------------
// K1: projections + exponentials (FROZEN from R7).
//   eq  [row][h]             = exp2(ps * Q.Wq^T)   [2048][128]
//   ekt4[b][h4][j][c] (f32)  = exp2(ps * K.Wk^T), h=4*h4+c
// ---------------------------------------------------------------------------
__global__ __launch_bounds__(256) void proj_kernel(
    const float* __restrict__ queries, const float* __restrict__ keys,
    const float4* __restrict__ wt,
    float* __restrict__ eq, float* __restrict__ ekt4f)
{
    const int bid   = blockIdx.x;        // 512 = 2 which * 256 row-tiles(8)
    const int which = bid & 1;
    const int rt    = bid >> 1;
    const int row0  = rt * 8;
    const float4* In4 = (const float4*)(which ? keys : queries);
    const float4* w4  = wt + (size_t)which * 64 * NH;

    __shared__ float4 rows[8][64];       // 8KB

    const int t    = threadIdx.x;
    const int lane = t & 63;
    const int wid  = t >> 6;

    {   // stage 8 rows, coalesced
        const int f4 = t & 63;
        const int r  = t >> 6;
        rows[r][f4]     = In4[(size_t)(row0 + r) * 64 + f4];
        rows[r + 4][f4] = In4[(size_t)(row0 + r + 4) * 64 + f4];
    }
    __syncthreads();

    const int r0 = wid * 2;              // wave's 2 rows
    float acc[2][2] = {};
    #pragma unroll 4
    for (int f4 = 0; f4 < 64; ++f4) {
        const float4 w0 = w4[f4 * NH + lane];        // coalesced 1KB
        const float4 w1 = w4[f4 * NH + lane + 64];
        #pragma unroll
        for (int r = 0; r < 2; ++r) {
            const float4 x = rows[r0 + r][f4];       // wave-uniform broadcast
            acc[r][0] += w0.x * x.x + w0.y * x.y + w0.z * x.z + w0.w * x.w;
            acc[r][1] += w1.x * x.x + w1.y * x.y + w1.z * x.z + w1.w * x.w;
        }
    }

    if (which == 0) {
        #pragma unroll
        for (int r = 0; r < 2; ++r) {
            const size_t o = (size_t)(row0 + r0 + r) * NH;
            eq[o + lane]      = fexp2(kPreScale * acc[r][0]);
            eq[o + lane + 64] = fexp2(kPreScale * acc[r][1]);
        }
    } else {
        const int b  = row0 >> 9;
        const int j0 = (row0 & 511) + r0;
        #pragma unroll
        for (int r = 0; r < 2; ++r) {
            #pragma unroll
            for (int s = 0; s < 2; ++s) {
                const int h = lane + 64 * s;
                ekt4f[(((size_t)b * 32 + (h >> 2)) * LK + j0 + r) * 4 + (h & 3)]
                    = fexp2(kPreScale * acc[r][s]);
            }
        }
    }
}

// ---------------------------------------------------------------------------
// K2 (FUSED, R6 structure + float4 Ek loads, unroll 4 = VGPR-safe ~50):
// scores + softmax-sum + attn write + PV + out in one kernel.
// Block = (b, 4-query tile); 1024 threads = 16 waves; grid 512, b fastest.
//
// Phase S: wave (qi = w&3, g = w>>2) computes p = exp(s - M) for query qi,
//   chunks {g, g+4}.  M = sum|W_v| >= max score -> no row-max pass.
//   KEY CHANGE vs R6 (measured 43.9us, VALUBusy 31%): Ek read as float4
//   (4 h-values, 16B/lane) -> 32 VMEM instr per j instead of 128 scalar;
//   unroll 4 keeps ~4 loads in flight at ~50 VGPR (no spill; R7's unroll-8
//   under a 64-VGPR cap likely spilled, which is why its fix never showed).
// Norm: shfl + reds[16] -> rs; attn -> global (coalesced) + attn_t[j][4].
// Phase PV: wave w owns j in [32w, 32w+32): per j, 1 uniform b128 gives all
//   4 q-weights, 1 coalesced 1KB values load, 16 fma; two-round pacc reduce.
// ---------------------------------------------------------------------------
__global__ __launch_bounds__(1024, 8) void fused_kernel(
    const float* __restrict__ eq, const float* __restrict__ ekt4f,
    const float* __restrict__ values, const int* __restrict__ valid_lens,
    const float* __restrict__ W_v,
    float* __restrict__ out, float* __restrict__ attn_out)
{
    const int id = blockIdx.x;           // 512 = 128 qt * 4 b (b fastest)
    const int b  = id & 3;
    const int i0 = (id >> 2) * 4;
    const int vl = valid_lens[b];

    __shared__ float  eq_lds[4][NH];
    __shared__ float  wv[NH];
    __shared__ float  attn_t[LK][4];     // [j][q], rows 16B-aligned
    __shared__ float4 pacc[8][4][VD / 4];
    __shared__ float  reds[16];

    const int t    = threadIdx.x;
    const int wid  = t >> 6;
    const int lane = t & 63;
    const int qi   = wid & 3;
    const int g    = wid >> 2;

    if (t < 4 * NH) ((float*)eq_lds)[t] = eq[(size_t)(b * LQ + i0) * NH + t];
    if (t < NH)     wv[t] = W_v[t];
    __syncthreads();

    const float4* q4  = (const float4*)eq_lds[qi];
    const float4* wv4 = (const float4*)wv;

    float sumA = 0.f, sumW = 0.f;
    #pragma unroll 8
    for (int h4 = 0; h4 < NH / 4; ++h4) {
        const float4 w = wv4[h4];
        sumW += (w.x + w.y) + (w.z + w.w);
        sumA += (fabsf(w.x) + fabsf(w.y)) + (fabsf(w.z) + fabsf(w.w));
    }

    // ---- Phase S: p for chunks {g, g+4} of query qi ----
    float p[2];
    float sum = 0.f;
    #pragma unroll
    for (int u = 0; u < 2; ++u) {
        const int jj = g + 4 * u;
        const int j  = jj * 64 + lane;
        float pv = 0.f;
        if (jj * 64 < vl) {              // wave-uniform
            const float4* pk4 = (const float4*)ekt4f + (size_t)b * 32 * LK + j;
            float a0 = 0.f, a1 = 0.f, a2 = 0.f, a3 = 0.f;
            #pragma unroll 4
            for (int h4 = 0; h4 < NH / 4; ++h4) {
                const float4 e = pk4[(size_t)h4 * LK];   // 16B/lane, 1KB/wave
                const float4 w = wv4[h4];
                const float4 q = q4[h4];
                a0 = __builtin_fmaf(w.x, frcp(__builtin_fmaf(q.x, e.x, 1.f)), a0);
                a1 = __builtin_fmaf(w.y, frcp(__builtin_fmaf(q.y, e.y, 1.f)), a1);
                a2 = __builtin_fmaf(w.z, frcp(__builtin_fmaf(q.z, e.z, 1.f)), a2);
                a3 = __builtin_fmaf(w.w, frcp(__builtin_fmaf(q.w, e.w, 1.f)), a3);
            }
            const float s = __builtin_fmaf(-2.f, (a0 + a1) + (a2 + a3), sumW);
            pv = fexp2((s - sumA) * kLog2e);
            if (j >= vl) pv = 0.f;       // mask tail of boundary chunk
        }
        p[u] = pv;
        sum += pv;
    }

    // ---- normalize: per-query sum across 4 g-waves ----
    #pragma unroll
    for (int off = 1; off < 64; off <<= 1)
        sum += __shfl_xor(sum, off, 64);
    if (lane == 0) reds[wid] = sum;
    __syncthreads();
    const float rs = frcp((reds[qi] + reds[qi + 4]) + (reds[qi + 8] + reds[qi + 12]));

    float* arow = attn_out + (size_t)(b * LQ + i0 + qi) * LK;
    #pragma unroll
    for (int u = 0; u < 2; ++u) {
        const int j = (g + 4 * u) * 64 + lane;
        const float a = p[u] * rs;
        arow[j]       = a;               // coalesced; zeros beyond vl
        attn_t[j][qi] = a;
    }
    __syncthreads();

    // ---- Phase PV ----
    const int j0 = wid * 32;
    const int j1 = min(j0 + 32, vl);     // attn_t exactly 0 in [vl, LK)
    float4 acc4[4];
    #pragma unroll
    for (int q = 0; q < 4; ++q) acc4[q] = float4{0.f, 0.f, 0.f, 0.f};

    const float4* v4 = (const float4*)(values + (size_t)b * LK * VD);
    for (int j = j0; j < j1; ++j) {
        const float4 a  = *(const float4*)&attn_t[j][0];   // all 4 q (uniform)
        const float4 vv = v4[(size_t)j * 64 + lane];       // coalesced 1KB
        fma4(acc4[0], a.x, vv);
        fma4(acc4[1], a.y, vv);
        fma4(acc4[2], a.z, vv);
        fma4(acc4[3], a.w, vv);
    }

    if (wid < 8) {
        #pragma unroll
        for (int q = 0; q < 4; ++q) pacc[wid][q][lane] = acc4[q];
    }
    __syncthreads();
    if (wid >= 8) {
        #pragma unroll
        for (int q = 0; q < 4; ++q) {
            const float4 pv = pacc[wid - 8][q][lane];
            pacc[wid - 8][q][lane] =
                float4{pv.x + acc4[q].x, pv.y + acc4[q].y,
                       pv.z + acc4[q].z, pv.w + acc4[q].w};
        }
    }
    __syncthreads();

    {   // final reduce: thread -> (q = t>>8, c = t&255)
        const int q = t >> 8;
        const int c = t & 255;
        float s = 0.f;
        #pragma unroll
        for (int k = 0; k < 8; ++k)
            s += ((const float*)&pacc[k][q][0])[c];
        out[(size_t)(b * LQ + i0 + q) * VD + c] = s;
    }
}

// ---------------------------------------------------------------------------
extern "C" void kernel_launch(void* const* d_in, const int* in_sizes, int n_in,
                              void* d_out, int out_size, void* d_ws, size_t ws_size,
                              hipStream_t stream)
{
    const float* queries    = (const float*)d_in[0];
    const float* keys       = (const float*)d_in[1];
    const float* values     = (const float*)d_in[2];
    const int*   valid_lens = (const int*)  d_in[3];
    const float* W_q        = (const float*)d_in[4];
    const float* W_k        = (const float*)d_in[5];
    const float* W_v        = (const float*)d_in[6];

    float* out      = (float*)d_out;                       // [NB, LQ, VD]
    float* attn_out = out + (size_t)NB * LQ * VD;          // [NB, LQ, LK]

    float*  eq    = (float*)d_ws;                          // [2048][128]  1MB
    float*  ekt4f = eq + (size_t)NB * LQ * NH;             // [4][32][512][4] 1MB
    float4* wt    = (float4*)(ekt4f + (size_t)NB * NH * LK); // [2][64][128] 256KB

    transw_kernel<<<16,  256,  0, stream>>>(W_q, W_k, wt);
    proj_kernel  <<<512, 256,  0, stream>>>(queries, keys, wt, eq, ekt4f);
    fused_kernel <<<512, 1024, 0, stream>>>(eq, ekt4f, values, valid_lens, W_v,
                                            out, attn_out);
}